// Round 11
// baseline (185.227 us; speedup 1.0000x reference)
//
#include <hip/hip_runtime.h>
#include <cstdint>
#include <cstddef>

#define ALPHA_ 0.25f
#define CLAMP_ 1e-4f
#define SCOPE_AGENT __HIP_MEMORY_SCOPE_AGENT

static constexpr int BLK = 256;
static constexpr int MAXB = 2048;

// ws layout (bytes). done[0..1] zeroed by pass1 block 0 (consumed by pass2/pass3
// in LATER dispatches -> ordered by dispatch boundaries). All other regions are
// written before read on every call -> poison-safe.
static constexpr size_t OFF_BCONF = 0;        // bconfT[32][MAXB] f32 (256 KB)
static constexpr size_t OFF_BVMAX = 262144;   // bvmaxT[32][MAXB] f32 (256 KB)
static constexpr size_t OFF_CONF = 524288;    // conf[32] f32
static constexpr size_t OFF_VMAX = 524416;    // vmax[32] f32
static constexpr size_t OFF_PART = 524544;    // partial[MAXB] f32 (8 KB)
static constexpr size_t OFF_DONE = 532736;    // done[2] u32
static constexpr size_t OFF_BITS = 1048576;   // maskbits[N] u32 (4 MB @ N=1e6)

__device__ inline unsigned int mask_from_row(const int* __restrict__ boxes, size_t i) {
    const int4* row = (const int4*)(boxes + i * 32);
    unsigned int m = 0u;
#pragma unroll
    for (int q = 0; q < 8; ++q) {
        int4 v = row[q];
        m |= (v.x > 0 ? 1u : 0u) << (4 * q + 0);
        m |= (v.y > 0 ? 1u : 0u) << (4 * q + 1);
        m |= (v.z > 0 ? 1u : 0u) << (4 * q + 2);
        m |= (v.w > 0 ? 1u : 0u) << (4 * q + 3);
    }
    return m;
}

// Pass 1: flat, fully-coalesced int4 stream over boxes (r5-proven, unchanged).
#define PROC1(a, s, idx, act)                                                     \
    {                                                                             \
        unsigned int nib = (unsigned int)((a).x > 0) |                            \
                           ((unsigned int)((a).y > 0) << 1) |                     \
                           ((unsigned int)((a).z > 0) << 2) |                     \
                           ((unsigned int)((a).w > 0) << 3);                      \
        unsigned int mm = nib << (4 * q);                                         \
        mm |= (unsigned int)__shfl_xor((int)mm, 1);                               \
        mm |= (unsigned int)__shfl_xor((int)mm, 2);                               \
        mm |= (unsigned int)__shfl_xor((int)mm, 4);                               \
        if (WRITEBITS && (act) && q == 0) maskbits[(idx) >> 3] = mm;              \
        c0 = fmaxf(c0, (nib & 1u) ? (s) : 0.0f);                                 \
        c1 = fmaxf(c1, (nib & 2u) ? (s) : 0.0f);                                 \
        c2 = fmaxf(c2, (nib & 4u) ? (s) : 0.0f);                                 \
        c3 = fmaxf(c3, (nib & 8u) ? (s) : 0.0f);                                 \
    }

template <bool WRITEBITS>
__global__ void __launch_bounds__(BLK) k_pass1(const int4* __restrict__ boxes4,
                                               const float* __restrict__ scores,
                                               unsigned int* __restrict__ maskbits,
                                               float* __restrict__ bconfT,
                                               unsigned int* __restrict__ done, size_t total4) {
    __shared__ unsigned int sconf[32];
    const int t = threadIdx.x;
    if (blockIdx.x == 0 && t == 0) {
        done[0] = 0u;  // for pass2 (later dispatch)
        done[1] = 0u;  // for pass3
    }
    if (t < 32) sconf[t] = 0u;
    __syncthreads();
    const int lane = t & 63;
    const int q = lane & 7;  // this thread owns columns 4q..4q+3
    float c0 = 0.0f, c1 = 0.0f, c2 = 0.0f, c3 = 0.0f;
    const size_t stride = (size_t)gridDim.x * BLK;
    size_t wb = (size_t)blockIdx.x * BLK + (size_t)(t - lane);  // wave-uniform base
    for (; wb + 3 * stride + 64 <= total4; wb += 4 * stride) {
        const size_t i0 = wb + lane, i1 = i0 + stride, i2 = i1 + stride, i3 = i2 + stride;
        int4 a0 = boxes4[i0];
        int4 a1 = boxes4[i1];
        int4 a2 = boxes4[i2];
        int4 a3 = boxes4[i3];
        float s0 = scores[i0 >> 3];
        float s1 = scores[i1 >> 3];
        float s2 = scores[i2 >> 3];
        float s3 = scores[i3 >> 3];
        PROC1(a0, s0, i0, true)
        PROC1(a1, s1, i1, true)
        PROC1(a2, s2, i2, true)
        PROC1(a3, s3, i3, true)
    }
    for (; wb < total4; wb += stride) {
        const size_t i = wb + lane;
        const bool act = i < total4;
        int4 a = {0, 0, 0, 0};
        float s = 0.0f;
        if (act) {
            a = boxes4[i];
            s = scores[i >> 3];
        }
        PROC1(a, s, i, act)
    }
#pragma unroll
    for (int off = 8; off < 64; off <<= 1) {
        c0 = fmaxf(c0, __shfl_xor(c0, off));
        c1 = fmaxf(c1, __shfl_xor(c1, off));
        c2 = fmaxf(c2, __shfl_xor(c2, off));
        c3 = fmaxf(c3, __shfl_xor(c3, off));
    }
    if (lane < 8) {  // q == lane
        atomicMax(&sconf[4 * q + 0], __float_as_uint(c0));
        atomicMax(&sconf[4 * q + 1], __float_as_uint(c1));
        atomicMax(&sconf[4 * q + 2], __float_as_uint(c2));
        atomicMax(&sconf[4 * q + 3], __float_as_uint(c3));
    }
    __syncthreads();
    if (t < 32) bconfT[(size_t)t * MAXB + blockIdx.x] = __uint_as_float(sconf[t]);
}

// Parallel reducer: 32 blocks, block g reduces contiguous srcT[g][0..nb) -> dst[g].
__global__ void __launch_bounds__(BLK) k_redmax(const float* __restrict__ srcT,
                                                float* __restrict__ dst, int nb) {
    __shared__ float sw[BLK / 64];
    const int g = blockIdx.x;
    const int t = threadIdx.x;
    const float* col = srcT + (size_t)g * MAXB;
    float m = 0.0f;  // all values >= 0
    for (int j = t; j < nb; j += BLK) m = fmaxf(m, col[j]);
#pragma unroll
    for (int off = 32; off > 0; off >>= 1) m = fmaxf(m, __shfl_xor(m, off));
    if ((t & 63) == 0) sw[t >> 6] = m;
    __syncthreads();
    if (t == 0) dst[g] = fmaxf(fmaxf(sw[0], sw[1]), fmaxf(sw[2], sw[3]));
}

// Pass 2 (column-chunked, 4 x 8 columns -> no spills): vmax partials;
// LAST block (plain stores + one threadfence + one atomicAdd) reduces -> vmax.
template <bool USEBITS>
__global__ void __launch_bounds__(BLK) k_pass2(const unsigned int* __restrict__ maskbits,
                                               const int* __restrict__ boxes,
                                               const float* __restrict__ scores,
                                               const float* __restrict__ ious,
                                               const float* __restrict__ conf,
                                               float* __restrict__ bvmaxT,
                                               float* __restrict__ vmax,
                                               unsigned int* __restrict__ done, int n) {
    __shared__ float scf[32];
    __shared__ unsigned int svm[32];
    __shared__ int slast;
    const int t = threadIdx.x;
    const int lane = t & 63;
    if (t < 32) {
        scf[t] = conf[t];
        svm[t] = 0u;
    }
    __syncthreads();
    const size_t stride = (size_t)gridDim.x * BLK;
#pragma unroll 1
    for (int c = 0; c < 4; ++c) {
        float cf[8], vm[8];
#pragma unroll
        for (int j = 0; j < 8; ++j) {
            cf[j] = scf[8 * c + j];
            vm[j] = 0.0f;
        }
        for (size_t i = (size_t)blockIdx.x * BLK + t; i < (size_t)n; i += stride) {
            unsigned int mc = (USEBITS ? maskbits[i] : mask_from_row(boxes, i)) >> (8 * c);
            float ls = __logf(scores[i]);
            float iou = ious[i];
#pragma unroll
            for (int j = 0; j < 8; ++j) {
                float v = __expf(cf[j] * ls) * iou;
                vm[j] = fmaxf(vm[j], ((mc >> j) & 1u) ? v : 0.0f);
            }
        }
#pragma unroll
        for (int j = 0; j < 8; ++j) {
#pragma unroll
            for (int off = 32; off > 0; off >>= 1) vm[j] = fmaxf(vm[j], __shfl_xor(vm[j], off));
        }
        if (lane == 0) {
#pragma unroll
            for (int j = 0; j < 8; ++j) atomicMax(&svm[8 * c + j], __float_as_uint(vm[j]));
        }
    }
    __syncthreads();
    if (t < 32) bvmaxT[(size_t)t * MAXB + blockIdx.x] = __uint_as_float(svm[t]);  // wave 0
    if (t == 0) {
        __threadfence();  // flush this block's stores once
        unsigned int old = atomicAdd(done, 1u);
        slast = (old == gridDim.x - 1) ? 1 : 0;
    }
    __syncthreads();
    if (!slast) return;
    // R2 (last block): vmax[g] = max_j bvmaxT[g][j]; 4 accumulators for ILP
    __shared__ unsigned int sm2[32];
    if (t < 32) sm2[t] = 0u;
    __syncthreads();
    {
        const int col = t & 31;
        const int r0 = t >> 5;  // 8 row-groups
        const float* src = bvmaxT + (size_t)col * MAXB;
        float m0 = 0.0f, m1 = 0.0f, m2 = 0.0f, m3 = 0.0f;
        int j = r0;
        for (; j + 24 < (int)gridDim.x; j += 32) {
            m0 = fmaxf(m0, __hip_atomic_load(&src[j], __ATOMIC_RELAXED, SCOPE_AGENT));
            m1 = fmaxf(m1, __hip_atomic_load(&src[j + 8], __ATOMIC_RELAXED, SCOPE_AGENT));
            m2 = fmaxf(m2, __hip_atomic_load(&src[j + 16], __ATOMIC_RELAXED, SCOPE_AGENT));
            m3 = fmaxf(m3, __hip_atomic_load(&src[j + 24], __ATOMIC_RELAXED, SCOPE_AGENT));
        }
        for (; j < (int)gridDim.x; j += 8)
            m0 = fmaxf(m0, __hip_atomic_load(&src[j], __ATOMIC_RELAXED, SCOPE_AGENT));
        m0 = fmaxf(fmaxf(m0, m1), fmaxf(m2, m3));
        atomicMax(&sm2[col], __float_as_uint(m0));
    }
    __syncthreads();
    if (t < 32) vmax[t] = __uint_as_float(sm2[t]);
}

// Pass 3 (column-chunked): per-row loss -> block partials; LAST block sums -> out.
template <bool USEBITS>
__global__ void __launch_bounds__(BLK) k_pass3(const unsigned int* __restrict__ maskbits,
                                               const int* __restrict__ boxes,
                                               const float* __restrict__ scores,
                                               const float* __restrict__ ious,
                                               const float* __restrict__ logits,
                                               const float* __restrict__ conf,
                                               const float* __restrict__ vmax,
                                               float* __restrict__ partial,
                                               unsigned int* __restrict__ done,
                                               const unsigned int* __restrict__ npos_raw,
                                               float* __restrict__ out, int n) {
    __shared__ float scf[32], srv[32];
    __shared__ float swsum[BLK / 64];
    __shared__ int slast;
    const int t = threadIdx.x;
    if (t < 32) {
        scf[t] = conf[t];
        srv[t] = 1.0f / (vmax[t] + CLAMP_);
    }
    __syncthreads();
    float accpos = 0.0f;  // sum of logp*s1 + log1mp*s2  (scaled by -ALPHA later)
    float accneg = 0.0f;  // sum of -log(1-p)*p^2 over empty rows (scaled by 1-ALPHA)
    const size_t stride = (size_t)gridDim.x * BLK;
#pragma unroll 1
    for (int c = 0; c < 4; ++c) {
        float cf[8], rv[8];
#pragma unroll
        for (int j = 0; j < 8; ++j) {
            cf[j] = scf[8 * c + j];
            rv[j] = srv[8 * c + j];
        }
        for (size_t i = (size_t)blockIdx.x * BLK + t; i < (size_t)n; i += stride) {
            unsigned int m = USEBITS ? maskbits[i] : mask_from_row(boxes, i);
            float x = logits[i];
            float p = 1.0f / (1.0f + __expf(-x));
            p = fminf(fmaxf(p, CLAMP_), 1.0f - CLAMP_);
            float qq = 1.0f - p;
            float log1mp = __logf(qq);
            if (m == 0u) {
                if (c == 0) accneg += -log1mp * p * p;  // count the empty-row term once
            } else {
                float logp = __logf(p);
                float ls = __logf(scores[i]);
                float iou = ious[i];
                unsigned int mc = m >> (8 * c);
                float s1 = 0.0f, s2 = 0.0f;
#pragma unroll
                for (int j = 0; j < 8; ++j) {
                    float val = __expf(cf[j] * ls) * iou;
                    float w = (val + CLAMP_) * rv[j];
                    w = fminf(fmaxf(w, CLAMP_), 1.0f - CLAMP_);
                    float a = w * qq;
                    float b = (1.0f - w) * p;
                    bool on = (mc >> j) & 1u;
                    s1 += on ? a * a : 0.0f;
                    s2 += on ? b * b : 0.0f;
                }
                accpos += logp * s1 + log1mp * s2;
            }
        }
    }
    float tot = (1.0f - ALPHA_) * accneg - ALPHA_ * accpos;
#pragma unroll
    for (int off = 32; off > 0; off >>= 1) tot += __shfl_xor(tot, off);
    if ((t & 63) == 0) swsum[t >> 6] = tot;
    __syncthreads();
    if (t == 0) {
        partial[blockIdx.x] = swsum[0] + swsum[1] + swsum[2] + swsum[3];
        __threadfence();
        unsigned int old = atomicAdd(done, 1u);
        slast = (old == gridDim.x - 1) ? 1 : 0;
    }
    __syncthreads();
    if (!slast) return;
    // Final (last block): sum partials, divide by num_pos_avg
    float s = 0.0f;
    for (int j = t; j < (int)gridDim.x; j += BLK)
        s += __hip_atomic_load(&partial[j], __ATOMIC_RELAXED, SCOPE_AGENT);
#pragma unroll
    for (int off = 32; off > 0; off >>= 1) s += __shfl_xor(s, off);
    if ((t & 63) == 0) swsum[t >> 6] = s;
    __syncthreads();
    if (t == 0) {
        const float ttot = swsum[0] + swsum[1] + swsum[2] + swsum[3];
        const unsigned int v = *npos_raw;
        // num_pos_avg: int32 if exponent bits clear (small int), else float32 bits
        const float np = (v & 0x7f800000u) ? __uint_as_float(v) : (float)(int)v;
        out[0] = ttot / np;
    }
}

extern "C" void kernel_launch(void* const* d_in, const int* in_sizes, int n_in,
                              void* d_out, int out_size, void* d_ws, size_t ws_size,
                              hipStream_t stream) {
    const float* logits = (const float*)d_in[0];
    const float* scores = (const float*)d_in[1];
    const float* ious = (const float*)d_in[2];
    const int* boxes = (const int*)d_in[3];
    // d_in[4] = gt_labels (all zeros; scores/IoUMap have a single column) -> ignored
    const unsigned int* npos_raw = (const unsigned int*)d_in[5];
    float* out = (float*)d_out;
    const int n = in_sizes[0];
    const size_t total4 = (size_t)n * 8;  // flat int4 count of is_in_boxes

    unsigned char* ws = (unsigned char*)d_ws;
    float* bconfT = (float*)(ws + OFF_BCONF);
    float* bvmaxT = (float*)(ws + OFF_BVMAX);
    float* conf = (float*)(ws + OFF_CONF);
    float* vmax = (float*)(ws + OFF_VMAX);
    float* partial = (float*)(ws + OFF_PART);
    unsigned int* done = (unsigned int*)(ws + OFF_DONE);
    unsigned int* maskbits = (unsigned int*)(ws + OFF_BITS);
    const bool usebits = ws_size >= OFF_BITS + (size_t)n * 4u;

    int nbfull = (n + BLK - 1) / BLK;
    int nb = nbfull < MAXB ? nbfull : MAXB;
    int nb1full = (int)((total4 + BLK - 1) / BLK);
    int nb1 = nb1full < MAXB ? nb1full : MAXB;

    if (usebits) {
        k_pass1<true><<<dim3(nb1), dim3(BLK), 0, stream>>>((const int4*)boxes, scores, maskbits,
                                                           bconfT, done, total4);
        k_redmax<<<dim3(32), dim3(BLK), 0, stream>>>(bconfT, conf, nb1);
        k_pass2<true><<<dim3(nb), dim3(BLK), 0, stream>>>(maskbits, boxes, scores, ious, conf,
                                                          bvmaxT, vmax, &done[0], n);
        k_pass3<true><<<dim3(nb), dim3(BLK), 0, stream>>>(maskbits, boxes, scores, ious, logits,
                                                          conf, vmax, partial, &done[1], npos_raw,
                                                          out, n);
    } else {
        k_pass1<false><<<dim3(nb1), dim3(BLK), 0, stream>>>((const int4*)boxes, scores, maskbits,
                                                            bconfT, done, total4);
        k_redmax<<<dim3(32), dim3(BLK), 0, stream>>>(bconfT, conf, nb1);
        k_pass2<false><<<dim3(nb), dim3(BLK), 0, stream>>>(maskbits, boxes, scores, ious, conf,
                                                           bvmaxT, vmax, &done[0], n);
        k_pass3<false><<<dim3(nb), dim3(BLK), 0, stream>>>(maskbits, boxes, scores, ious, logits,
                                                           conf, vmax, partial, &done[1], npos_raw,
                                                           out, n);
    }
}

// Round 12
// 109.087 us; speedup vs baseline: 1.6980x; 1.6980x over previous
//
#include <hip/hip_runtime.h>
#include <cstdint>
#include <cstddef>

#define ALPHA_ 0.25f
#define CLAMP_ 1e-4f

static constexpr int BLK = 256;
static constexpr int MAXB = 2048;
static constexpr int CSTR = 32;  // uints per padded cell (128 B = own cacheline/slice)

// ws layout (bytes). conf/vmax cells zeroed by k_init each call (atomicMax targets);
// everything else is written before read each call -> poison-safe.
static constexpr size_t OFF_CONF = 0;       // conf_u[32] padded x128B (4 KB)
static constexpr size_t OFF_VMAX = 4096;    // vmax_u[32] padded x128B (4 KB)
static constexpr size_t OFF_PART = 8192;    // partial[MAXB] f32 (8 KB)
static constexpr size_t OFF_BITS = 65536;   // maskbits[N] u32 (4 MB @ N=1e6)

__global__ void k_init(unsigned int* hdr) {
    // zero conf+vmax padded cells: 8192 B = 2048 words
    const int t = threadIdx.x;
#pragma unroll
    for (int j = 0; j < 8; ++j) hdr[t + j * BLK] = 0u;
}

__device__ inline unsigned int mask_from_row(const int* __restrict__ boxes, size_t i) {
    const int4* row = (const int4*)(boxes + i * 32);
    unsigned int m = 0u;
#pragma unroll
    for (int q = 0; q < 8; ++q) {
        int4 v = row[q];
        m |= (v.x > 0 ? 1u : 0u) << (4 * q + 0);
        m |= (v.y > 0 ? 1u : 0u) << (4 * q + 1);
        m |= (v.z > 0 ? 1u : 0u) << (4 * q + 2);
        m |= (v.w > 0 ? 1u : 0u) << (4 * q + 3);
    }
    return m;
}

// Pass 1: flat, fully-coalesced int4 stream over boxes (r5-proven body).
// Tail: LDS-staged block maxima -> 32 PADDED global atomicMax cells (each on its
// own cacheline -> parallel L2 slices, fire-and-forget, hidden under the stream).
#define PROC1(a, s, idx, act)                                                     \
    {                                                                             \
        unsigned int nib = (unsigned int)((a).x > 0) |                            \
                           ((unsigned int)((a).y > 0) << 1) |                     \
                           ((unsigned int)((a).z > 0) << 2) |                     \
                           ((unsigned int)((a).w > 0) << 3);                      \
        unsigned int mm = nib << (4 * q);                                         \
        mm |= (unsigned int)__shfl_xor((int)mm, 1);                               \
        mm |= (unsigned int)__shfl_xor((int)mm, 2);                               \
        mm |= (unsigned int)__shfl_xor((int)mm, 4);                               \
        if (WRITEBITS && (act) && q == 0) maskbits[(idx) >> 3] = mm;              \
        c0 = fmaxf(c0, (nib & 1u) ? (s) : 0.0f);                                 \
        c1 = fmaxf(c1, (nib & 2u) ? (s) : 0.0f);                                 \
        c2 = fmaxf(c2, (nib & 4u) ? (s) : 0.0f);                                 \
        c3 = fmaxf(c3, (nib & 8u) ? (s) : 0.0f);                                 \
    }

template <bool WRITEBITS>
__global__ void __launch_bounds__(BLK) k_pass1(const int4* __restrict__ boxes4,
                                               const float* __restrict__ scores,
                                               unsigned int* __restrict__ maskbits,
                                               unsigned int* __restrict__ conf_u,
                                               size_t total4) {
    __shared__ unsigned int sconf[32];
    const int t = threadIdx.x;
    if (t < 32) sconf[t] = 0u;
    __syncthreads();
    const int lane = t & 63;
    const int q = lane & 7;  // this thread owns columns 4q..4q+3
    float c0 = 0.0f, c1 = 0.0f, c2 = 0.0f, c3 = 0.0f;
    const size_t stride = (size_t)gridDim.x * BLK;
    size_t wb = (size_t)blockIdx.x * BLK + (size_t)(t - lane);  // wave-uniform base
    for (; wb + 3 * stride + 64 <= total4; wb += 4 * stride) {
        const size_t i0 = wb + lane, i1 = i0 + stride, i2 = i1 + stride, i3 = i2 + stride;
        int4 a0 = boxes4[i0];
        int4 a1 = boxes4[i1];
        int4 a2 = boxes4[i2];
        int4 a3 = boxes4[i3];
        float s0 = scores[i0 >> 3];
        float s1 = scores[i1 >> 3];
        float s2 = scores[i2 >> 3];
        float s3 = scores[i3 >> 3];
        PROC1(a0, s0, i0, true)
        PROC1(a1, s1, i1, true)
        PROC1(a2, s2, i2, true)
        PROC1(a3, s3, i3, true)
    }
    for (; wb < total4; wb += stride) {
        const size_t i = wb + lane;
        const bool act = i < total4;
        int4 a = {0, 0, 0, 0};
        float s = 0.0f;
        if (act) {
            a = boxes4[i];
            s = scores[i >> 3];
        }
        PROC1(a, s, i, act)
    }
#pragma unroll
    for (int off = 8; off < 64; off <<= 1) {
        c0 = fmaxf(c0, __shfl_xor(c0, off));
        c1 = fmaxf(c1, __shfl_xor(c1, off));
        c2 = fmaxf(c2, __shfl_xor(c2, off));
        c3 = fmaxf(c3, __shfl_xor(c3, off));
    }
    if (lane < 8) {  // q == lane
        atomicMax(&sconf[4 * q + 0], __float_as_uint(c0));
        atomicMax(&sconf[4 * q + 1], __float_as_uint(c1));
        atomicMax(&sconf[4 * q + 2], __float_as_uint(c2));
        atomicMax(&sconf[4 * q + 3], __float_as_uint(c3));
    }
    __syncthreads();
    if (t < 32) atomicMax(&conf_u[(size_t)t * CSTR], sconf[t]);  // padded cells
}

// Pass 2 (column-chunked 4x8, r11-proven body, NO fence tail): vmax funnel into
// padded cells.
template <bool USEBITS>
__global__ void __launch_bounds__(BLK) k_pass2(const unsigned int* __restrict__ maskbits,
                                               const int* __restrict__ boxes,
                                               const float* __restrict__ scores,
                                               const float* __restrict__ ious,
                                               const unsigned int* __restrict__ conf_u,
                                               unsigned int* __restrict__ vmax_u, int n) {
    __shared__ float scf[32];
    __shared__ unsigned int svm[32];
    const int t = threadIdx.x;
    const int lane = t & 63;
    if (t < 32) {
        scf[t] = __uint_as_float(conf_u[(size_t)t * CSTR]);
        svm[t] = 0u;
    }
    __syncthreads();
    const size_t stride = (size_t)gridDim.x * BLK;
#pragma unroll 1
    for (int c = 0; c < 4; ++c) {
        float cf[8], vm[8];
#pragma unroll
        for (int j = 0; j < 8; ++j) {
            cf[j] = scf[8 * c + j];
            vm[j] = 0.0f;
        }
        for (size_t i = (size_t)blockIdx.x * BLK + t; i < (size_t)n; i += stride) {
            unsigned int mc = (USEBITS ? maskbits[i] : mask_from_row(boxes, i)) >> (8 * c);
            float ls = __logf(scores[i]);
            float iou = ious[i];
#pragma unroll
            for (int j = 0; j < 8; ++j) {
                float v = __expf(cf[j] * ls) * iou;
                vm[j] = fmaxf(vm[j], ((mc >> j) & 1u) ? v : 0.0f);
            }
        }
#pragma unroll
        for (int j = 0; j < 8; ++j) {
#pragma unroll
            for (int off = 32; off > 0; off >>= 1) vm[j] = fmaxf(vm[j], __shfl_xor(vm[j], off));
        }
        if (lane == 0) {
#pragma unroll
            for (int j = 0; j < 8; ++j) atomicMax(&svm[8 * c + j], __float_as_uint(vm[j]));
        }
    }
    __syncthreads();
    if (t < 32) atomicMax(&vmax_u[(size_t)t * CSTR], svm[t]);  // padded cells
}

// Pass 3 (column-chunked, r11-proven body, NO fence tail): block partial sums.
template <bool USEBITS>
__global__ void __launch_bounds__(BLK) k_pass3(const unsigned int* __restrict__ maskbits,
                                               const int* __restrict__ boxes,
                                               const float* __restrict__ scores,
                                               const float* __restrict__ ious,
                                               const float* __restrict__ logits,
                                               const unsigned int* __restrict__ conf_u,
                                               const unsigned int* __restrict__ vmax_u,
                                               float* __restrict__ partial, int n) {
    __shared__ float scf[32], srv[32];
    __shared__ float swsum[BLK / 64];
    const int t = threadIdx.x;
    if (t < 32) {
        scf[t] = __uint_as_float(conf_u[(size_t)t * CSTR]);
        srv[t] = 1.0f / (__uint_as_float(vmax_u[(size_t)t * CSTR]) + CLAMP_);
    }
    __syncthreads();
    float accpos = 0.0f;  // sum of logp*s1 + log1mp*s2  (scaled by -ALPHA later)
    float accneg = 0.0f;  // sum of -log(1-p)*p^2 over empty rows (scaled by 1-ALPHA)
    const size_t stride = (size_t)gridDim.x * BLK;
#pragma unroll 1
    for (int c = 0; c < 4; ++c) {
        float cf[8], rv[8];
#pragma unroll
        for (int j = 0; j < 8; ++j) {
            cf[j] = scf[8 * c + j];
            rv[j] = srv[8 * c + j];
        }
        for (size_t i = (size_t)blockIdx.x * BLK + t; i < (size_t)n; i += stride) {
            unsigned int m = USEBITS ? maskbits[i] : mask_from_row(boxes, i);
            float x = logits[i];
            float p = 1.0f / (1.0f + __expf(-x));
            p = fminf(fmaxf(p, CLAMP_), 1.0f - CLAMP_);
            float qq = 1.0f - p;
            float log1mp = __logf(qq);
            if (m == 0u) {
                if (c == 0) accneg += -log1mp * p * p;  // count empty-row term once
            } else {
                float logp = __logf(p);
                float ls = __logf(scores[i]);
                float iou = ious[i];
                unsigned int mc = m >> (8 * c);
                float s1 = 0.0f, s2 = 0.0f;
#pragma unroll
                for (int j = 0; j < 8; ++j) {
                    float val = __expf(cf[j] * ls) * iou;
                    float w = (val + CLAMP_) * rv[j];
                    w = fminf(fmaxf(w, CLAMP_), 1.0f - CLAMP_);
                    float a = w * qq;
                    float b = (1.0f - w) * p;
                    bool on = (mc >> j) & 1u;
                    s1 += on ? a * a : 0.0f;
                    s2 += on ? b * b : 0.0f;
                }
                accpos += logp * s1 + log1mp * s2;
            }
        }
    }
    float tot = (1.0f - ALPHA_) * accneg - ALPHA_ * accpos;
#pragma unroll
    for (int off = 32; off > 0; off >>= 1) tot += __shfl_xor(tot, off);
    if ((t & 63) == 0) swsum[t >> 6] = tot;
    __syncthreads();
    if (t == 0) partial[blockIdx.x] = swsum[0] + swsum[1] + swsum[2] + swsum[3];
}

__global__ void __launch_bounds__(BLK) k_fin(const float* __restrict__ partial, int nb,
                                             const unsigned int* __restrict__ npos_raw,
                                             float* __restrict__ out) {
    __shared__ float sw[BLK / 64];
    const int t = threadIdx.x;
    float s = 0.0f;
    for (int i = t; i < nb; i += BLK) s += partial[i];  // <=8 independent loads/thread
#pragma unroll
    for (int off = 32; off > 0; off >>= 1) s += __shfl_xor(s, off);
    if ((t & 63) == 0) sw[t >> 6] = s;
    __syncthreads();
    if (t == 0) {
        const float tot = sw[0] + sw[1] + sw[2] + sw[3];
        const unsigned int v = *npos_raw;
        // num_pos_avg: int32 if exponent bits clear (small int), else float32 bits
        const float np = (v & 0x7f800000u) ? __uint_as_float(v) : (float)(int)v;
        out[0] = tot / np;
    }
}

extern "C" void kernel_launch(void* const* d_in, const int* in_sizes, int n_in,
                              void* d_out, int out_size, void* d_ws, size_t ws_size,
                              hipStream_t stream) {
    const float* logits = (const float*)d_in[0];
    const float* scores = (const float*)d_in[1];
    const float* ious = (const float*)d_in[2];
    const int* boxes = (const int*)d_in[3];
    // d_in[4] = gt_labels (all zeros; scores/IoUMap have a single column) -> ignored
    const unsigned int* npos_raw = (const unsigned int*)d_in[5];
    float* out = (float*)d_out;
    const int n = in_sizes[0];
    const size_t total4 = (size_t)n * 8;  // flat int4 count of is_in_boxes

    unsigned char* ws = (unsigned char*)d_ws;
    unsigned int* conf_u = (unsigned int*)(ws + OFF_CONF);
    unsigned int* vmax_u = (unsigned int*)(ws + OFF_VMAX);
    float* partial = (float*)(ws + OFF_PART);
    unsigned int* maskbits = (unsigned int*)(ws + OFF_BITS);
    const bool usebits = ws_size >= OFF_BITS + (size_t)n * 4u;

    int nbfull = (n + BLK - 1) / BLK;
    int nb = nbfull < MAXB ? nbfull : MAXB;
    int nb1full = (int)((total4 + BLK - 1) / BLK);
    int nb1 = nb1full < MAXB ? nb1full : MAXB;

    k_init<<<dim3(1), dim3(BLK), 0, stream>>>((unsigned int*)ws);
    if (usebits) {
        k_pass1<true><<<dim3(nb1), dim3(BLK), 0, stream>>>((const int4*)boxes, scores, maskbits,
                                                           conf_u, total4);
        k_pass2<true><<<dim3(nb), dim3(BLK), 0, stream>>>(maskbits, boxes, scores, ious, conf_u,
                                                          vmax_u, n);
        k_pass3<true><<<dim3(nb), dim3(BLK), 0, stream>>>(maskbits, boxes, scores, ious, logits,
                                                          conf_u, vmax_u, partial, n);
    } else {
        k_pass1<false><<<dim3(nb1), dim3(BLK), 0, stream>>>((const int4*)boxes, scores, maskbits,
                                                            conf_u, total4);
        k_pass2<false><<<dim3(nb), dim3(BLK), 0, stream>>>(maskbits, boxes, scores, ious, conf_u,
                                                           vmax_u, n);
        k_pass3<false><<<dim3(nb), dim3(BLK), 0, stream>>>(maskbits, boxes, scores, ious, logits,
                                                           conf_u, vmax_u, partial, n);
    }
    k_fin<<<dim3(1), dim3(BLK), 0, stream>>>(partial, nb, npos_raw, out);
}

// Round 13
// 84.257 us; speedup vs baseline: 2.1983x; 1.2947x over previous
//
#include <hip/hip_runtime.h>
#include <cstdint>
#include <cstddef>

#define ALPHA_ 0.25f
#define CLAMP_ 1e-4f

static constexpr int BLK = 256;
static constexpr int MAXB = 2048;

// ws layout (bytes). Every region is written before it is read on every call,
// so no initialization kernel is needed (poison-safe).
// Block partials are stored TRANSPOSED (column-major: [32][MAXB]) so the
// 32-block parallel reducer reads each column contiguously.
static constexpr size_t OFF_BCONF = 0;        // bconfT[32][MAXB] f32 (256 KB)
static constexpr size_t OFF_BVMAX = 262144;   // bvmaxT[32][MAXB] f32 (256 KB)
static constexpr size_t OFF_CONF = 524288;    // conf[32] f32
static constexpr size_t OFF_VMAX = 524416;    // vmax[32] f32
static constexpr size_t OFF_PART = 524544;    // partial[MAXB] f32 (8 KB)
static constexpr size_t OFF_BITS = 1048576;   // maskbits[N] u32 (4 MB @ N=1e6)

__device__ inline unsigned int mask_from_row(const int* __restrict__ boxes, size_t i) {
    const int4* row = (const int4*)(boxes + i * 32);
    unsigned int m = 0u;
#pragma unroll
    for (int q = 0; q < 8; ++q) {
        int4 v = row[q];
        m |= (v.x > 0 ? 1u : 0u) << (4 * q + 0);
        m |= (v.y > 0 ? 1u : 0u) << (4 * q + 1);
        m |= (v.z > 0 ? 1u : 0u) << (4 * q + 2);
        m |= (v.w > 0 ? 1u : 0u) << (4 * q + 3);
    }
    return m;
}

// Pass 1 (r5-proven, unchanged): flat, fully-coalesced int4 stream over boxes.
#define PROC1(a, s, idx, act)                                                     \
    {                                                                             \
        unsigned int nib = (unsigned int)((a).x > 0) |                            \
                           ((unsigned int)((a).y > 0) << 1) |                     \
                           ((unsigned int)((a).z > 0) << 2) |                     \
                           ((unsigned int)((a).w > 0) << 3);                      \
        unsigned int mm = nib << (4 * q);                                         \
        mm |= (unsigned int)__shfl_xor((int)mm, 1);                               \
        mm |= (unsigned int)__shfl_xor((int)mm, 2);                               \
        mm |= (unsigned int)__shfl_xor((int)mm, 4);                               \
        if (WRITEBITS && (act) && q == 0) maskbits[(idx) >> 3] = mm;              \
        c0 = fmaxf(c0, (nib & 1u) ? (s) : 0.0f);                                 \
        c1 = fmaxf(c1, (nib & 2u) ? (s) : 0.0f);                                 \
        c2 = fmaxf(c2, (nib & 4u) ? (s) : 0.0f);                                 \
        c3 = fmaxf(c3, (nib & 8u) ? (s) : 0.0f);                                 \
    }

template <bool WRITEBITS>
__global__ void __launch_bounds__(BLK) k_pass1(const int4* __restrict__ boxes4,
                                               const float* __restrict__ scores,
                                               unsigned int* __restrict__ maskbits,
                                               float* __restrict__ bconfT, size_t total4) {
    __shared__ unsigned int sconf[32];
    const int t = threadIdx.x;
    if (t < 32) sconf[t] = 0u;
    __syncthreads();
    const int lane = t & 63;
    const int q = lane & 7;  // this thread owns columns 4q..4q+3
    float c0 = 0.0f, c1 = 0.0f, c2 = 0.0f, c3 = 0.0f;
    const size_t stride = (size_t)gridDim.x * BLK;
    size_t wb = (size_t)blockIdx.x * BLK + (size_t)(t - lane);  // wave-uniform base
    for (; wb + 3 * stride + 64 <= total4; wb += 4 * stride) {
        const size_t i0 = wb + lane, i1 = i0 + stride, i2 = i1 + stride, i3 = i2 + stride;
        int4 a0 = boxes4[i0];
        int4 a1 = boxes4[i1];
        int4 a2 = boxes4[i2];
        int4 a3 = boxes4[i3];
        float s0 = scores[i0 >> 3];
        float s1 = scores[i1 >> 3];
        float s2 = scores[i2 >> 3];
        float s3 = scores[i3 >> 3];
        PROC1(a0, s0, i0, true)
        PROC1(a1, s1, i1, true)
        PROC1(a2, s2, i2, true)
        PROC1(a3, s3, i3, true)
    }
    for (; wb < total4; wb += stride) {
        const size_t i = wb + lane;
        const bool act = i < total4;
        int4 a = {0, 0, 0, 0};
        float s = 0.0f;
        if (act) {
            a = boxes4[i];
            s = scores[i >> 3];
        }
        PROC1(a, s, i, act)
    }
#pragma unroll
    for (int off = 8; off < 64; off <<= 1) {
        c0 = fmaxf(c0, __shfl_xor(c0, off));
        c1 = fmaxf(c1, __shfl_xor(c1, off));
        c2 = fmaxf(c2, __shfl_xor(c2, off));
        c3 = fmaxf(c3, __shfl_xor(c3, off));
    }
    if (lane < 8) {  // q == lane
        atomicMax(&sconf[4 * q + 0], __float_as_uint(c0));
        atomicMax(&sconf[4 * q + 1], __float_as_uint(c1));
        atomicMax(&sconf[4 * q + 2], __float_as_uint(c2));
        atomicMax(&sconf[4 * q + 3], __float_as_uint(c3));
    }
    __syncthreads();
    if (t < 32) bconfT[(size_t)t * MAXB + blockIdx.x] = __uint_as_float(sconf[t]);
}

// Parallel reducer (r5-proven): 32 blocks, block g reduces srcT[g][0..nb) -> dst[g].
__global__ void __launch_bounds__(BLK) k_redmax(const float* __restrict__ srcT,
                                                float* __restrict__ dst, int nb) {
    __shared__ float sw[BLK / 64];
    const int g = blockIdx.x;
    const int t = threadIdx.x;
    const float* col = srcT + (size_t)g * MAXB;
    float m = 0.0f;  // all values >= 0
    for (int j = t; j < nb; j += BLK) m = fmaxf(m, col[j]);
#pragma unroll
    for (int off = 32; off > 0; off >>= 1) m = fmaxf(m, __shfl_xor(m, off));
    if ((t & 63) == 0) sw[t >> 6] = m;
    __syncthreads();
    if (t == 0) dst[g] = fmaxf(fmaxf(sw[0], sw[1]), fmaxf(sw[2], sw[3]));
}

// Pass 2 (2-chunk x 16 cols: cf[16]+vm[16] -> no spills): vmax block partials.
template <bool USEBITS>
__global__ void __launch_bounds__(BLK) k_pass2(const unsigned int* __restrict__ maskbits,
                                               const int* __restrict__ boxes,
                                               const float* __restrict__ scores,
                                               const float* __restrict__ ious,
                                               const float* __restrict__ conf,
                                               float* __restrict__ bvmaxT, int n) {
    __shared__ float scf[32];
    __shared__ unsigned int svm[32];
    const int t = threadIdx.x;
    const int lane = t & 63;
    if (t < 32) {
        scf[t] = conf[t];
        svm[t] = 0u;
    }
    __syncthreads();
    const size_t stride = (size_t)gridDim.x * BLK;
#pragma unroll 1
    for (int c = 0; c < 2; ++c) {
        float cf[16], vm[16];
#pragma unroll
        for (int j = 0; j < 16; ++j) {
            cf[j] = scf[16 * c + j];
            vm[j] = 0.0f;
        }
        for (size_t i = (size_t)blockIdx.x * BLK + t; i < (size_t)n; i += stride) {
            unsigned int mc = (USEBITS ? maskbits[i] : mask_from_row(boxes, i)) >> (16 * c);
            float ls = __logf(scores[i]);
            float iou = ious[i];
#pragma unroll
            for (int j = 0; j < 16; ++j) {
                float v = __expf(cf[j] * ls) * iou;
                vm[j] = fmaxf(vm[j], ((mc >> j) & 1u) ? v : 0.0f);
            }
        }
#pragma unroll
        for (int j = 0; j < 16; ++j) {
#pragma unroll
            for (int off = 32; off > 0; off >>= 1) vm[j] = fmaxf(vm[j], __shfl_xor(vm[j], off));
        }
        if (lane == 0) {
#pragma unroll
            for (int j = 0; j < 16; ++j) atomicMax(&svm[16 * c + j], __float_as_uint(vm[j]));
        }
    }
    __syncthreads();
    if (t < 32) bvmaxT[(size_t)t * MAXB + blockIdx.x] = __uint_as_float(svm[t]);
}

// Pass 3 (2-chunk x 16 cols: cf[16]+rv[16] -> no spills): loss block partials.
template <bool USEBITS>
__global__ void __launch_bounds__(BLK) k_pass3(const unsigned int* __restrict__ maskbits,
                                               const int* __restrict__ boxes,
                                               const float* __restrict__ scores,
                                               const float* __restrict__ ious,
                                               const float* __restrict__ logits,
                                               const float* __restrict__ conf,
                                               const float* __restrict__ vmax,
                                               float* __restrict__ partial, int n) {
    __shared__ float scf[32], srv[32];
    __shared__ float swsum[BLK / 64];
    const int t = threadIdx.x;
    if (t < 32) {
        scf[t] = conf[t];
        srv[t] = 1.0f / (vmax[t] + CLAMP_);
    }
    __syncthreads();
    float accpos = 0.0f;  // sum of logp*s1 + log1mp*s2  (scaled by -ALPHA later)
    float accneg = 0.0f;  // sum of -log(1-p)*p^2 over empty rows (scaled by 1-ALPHA)
    const size_t stride = (size_t)gridDim.x * BLK;
#pragma unroll 1
    for (int c = 0; c < 2; ++c) {
        float cf[16], rv[16];
#pragma unroll
        for (int j = 0; j < 16; ++j) {
            cf[j] = scf[16 * c + j];
            rv[j] = srv[16 * c + j];
        }
        for (size_t i = (size_t)blockIdx.x * BLK + t; i < (size_t)n; i += stride) {
            unsigned int m = USEBITS ? maskbits[i] : mask_from_row(boxes, i);
            float x = logits[i];
            float p = 1.0f / (1.0f + __expf(-x));
            p = fminf(fmaxf(p, CLAMP_), 1.0f - CLAMP_);
            float qq = 1.0f - p;
            float log1mp = __logf(qq);
            if (m == 0u) {
                if (c == 0) accneg += -log1mp * p * p;  // count empty-row term once
            } else {
                float logp = __logf(p);
                float ls = __logf(scores[i]);
                float iou = ious[i];
                unsigned int mc = m >> (16 * c);
                float s1 = 0.0f, s2 = 0.0f;
#pragma unroll
                for (int j = 0; j < 16; ++j) {
                    float val = __expf(cf[j] * ls) * iou;
                    float w = (val + CLAMP_) * rv[j];
                    w = fminf(fmaxf(w, CLAMP_), 1.0f - CLAMP_);
                    float a = w * qq;
                    float b = (1.0f - w) * p;
                    bool on = (mc >> j) & 1u;
                    s1 += on ? a * a : 0.0f;
                    s2 += on ? b * b : 0.0f;
                }
                accpos += logp * s1 + log1mp * s2;
            }
        }
    }
    float tot = (1.0f - ALPHA_) * accneg - ALPHA_ * accpos;
#pragma unroll
    for (int off = 32; off > 0; off >>= 1) tot += __shfl_xor(tot, off);
    if ((t & 63) == 0) swsum[t >> 6] = tot;
    __syncthreads();
    if (t == 0) partial[blockIdx.x] = swsum[0] + swsum[1] + swsum[2] + swsum[3];
}

__global__ void __launch_bounds__(BLK) k_fin(const float* __restrict__ partial, int nb,
                                             const unsigned int* __restrict__ npos_raw,
                                             float* __restrict__ out) {
    __shared__ float sw[BLK / 64];
    const int t = threadIdx.x;
    float s = 0.0f;
    for (int i = t; i < nb; i += BLK) s += partial[i];
#pragma unroll
    for (int off = 32; off > 0; off >>= 1) s += __shfl_xor(s, off);
    if ((t & 63) == 0) sw[t >> 6] = s;
    __syncthreads();
    if (t == 0) {
        const float tot = sw[0] + sw[1] + sw[2] + sw[3];
        const unsigned int v = *npos_raw;
        // num_pos_avg: int32 if exponent bits clear (small int), else float32 bits
        const float np = (v & 0x7f800000u) ? __uint_as_float(v) : (float)(int)v;
        out[0] = tot / np;
    }
}

extern "C" void kernel_launch(void* const* d_in, const int* in_sizes, int n_in,
                              void* d_out, int out_size, void* d_ws, size_t ws_size,
                              hipStream_t stream) {
    const float* logits = (const float*)d_in[0];
    const float* scores = (const float*)d_in[1];
    const float* ious = (const float*)d_in[2];
    const int* boxes = (const int*)d_in[3];
    // d_in[4] = gt_labels (all zeros; scores/IoUMap have a single column) -> ignored
    const unsigned int* npos_raw = (const unsigned int*)d_in[5];
    float* out = (float*)d_out;
    const int n = in_sizes[0];
    const size_t total4 = (size_t)n * 8;  // flat int4 count of is_in_boxes

    unsigned char* ws = (unsigned char*)d_ws;
    float* bconfT = (float*)(ws + OFF_BCONF);
    float* bvmaxT = (float*)(ws + OFF_BVMAX);
    float* conf = (float*)(ws + OFF_CONF);
    float* vmax = (float*)(ws + OFF_VMAX);
    float* partial = (float*)(ws + OFF_PART);
    unsigned int* maskbits = (unsigned int*)(ws + OFF_BITS);
    const bool usebits = ws_size >= OFF_BITS + (size_t)n * 4u;

    int nbfull = (n + BLK - 1) / BLK;
    int nb = nbfull < MAXB ? nbfull : MAXB;
    int nb1full = (int)((total4 + BLK - 1) / BLK);
    int nb1 = nb1full < MAXB ? nb1full : MAXB;

    if (usebits) {
        k_pass1<true><<<dim3(nb1), dim3(BLK), 0, stream>>>((const int4*)boxes, scores, maskbits,
                                                           bconfT, total4);
        k_redmax<<<dim3(32), dim3(BLK), 0, stream>>>(bconfT, conf, nb1);
        k_pass2<true><<<dim3(nb), dim3(BLK), 0, stream>>>(maskbits, boxes, scores, ious, conf,
                                                          bvmaxT, n);
        k_redmax<<<dim3(32), dim3(BLK), 0, stream>>>(bvmaxT, vmax, nb);
        k_pass3<true><<<dim3(nb), dim3(BLK), 0, stream>>>(maskbits, boxes, scores, ious, logits,
                                                          conf, vmax, partial, n);
    } else {
        k_pass1<false><<<dim3(nb1), dim3(BLK), 0, stream>>>((const int4*)boxes, scores, maskbits,
                                                            bconfT, total4);
        k_redmax<<<dim3(32), dim3(BLK), 0, stream>>>(bconfT, conf, nb1);
        k_pass2<false><<<dim3(nb), dim3(BLK), 0, stream>>>(maskbits, boxes, scores, ious, conf,
                                                           bvmaxT, n);
        k_redmax<<<dim3(32), dim3(BLK), 0, stream>>>(bvmaxT, vmax, nb);
        k_pass3<false><<<dim3(nb), dim3(BLK), 0, stream>>>(maskbits, boxes, scores, ious, logits,
                                                           conf, vmax, partial, n);
    }
    k_fin<<<dim3(1), dim3(BLK), 0, stream>>>(partial, nb, npos_raw, out);
}